// Round 2
// 143.807 us; speedup vs baseline: 1.0056x; 1.0056x over previous
//
#include <hip/hip_runtime.h>

// Dead-code-eliminated forward (verified rounds 0..3: cross-attention has ONE
// key/value -> softmax == 1 -> outputs depend only on:
//   ctx  = context_batch @ ctx_w + ctx_b
//   v    = ctx @ ca_wv + ca_bv
//   last = v @ ca_wo + ca_bo
//   pred = last @ pred_w[sid] + pred_b[sid]; act likewise).
//
// Round-5: rank-3 factorization, plain launches (cooperative launch crashes the
// graph-capture harness -- round-4 lesson).
//   ctx[b] = cb0*u0 + cb1*u1 + u2      (u0,u1 = ctx_w rows, u2 = ctx_b)
//   A_r = u_r @ ca_wv        (bv folded into A2 at K2 input)
//   B_r = A_r @ ca_wo        (bo folded into B2 at K3 input)
//   C_r = B_r @ {pred|act}_w[s];  out = cb0*C0 + cb1*C1 + C2 + bias
// Deterministic two-stage reductions through d_ws (no float atomics).

#define DD 512
#define BB 16
#define OO 64
#define NC 8   // d-chunks (reduction split) for K1/K2

// ---------------- K1: pA[db][r][j] = sum_{d in chunk db} u_r[d]*wv[d][j] ----
// grid 64 = (jb 8 x db 8), 256 threads = (dsub 4 x j 64)
__global__ __launch_bounds__(256) void k1_a(
    const float* __restrict__ cw, const float* __restrict__ cbias,
    const float* __restrict__ wv, float* __restrict__ pA) {
  __shared__ float ts[3 * 64];
  __shared__ float red[4 * 3 * 64];
  const int tid = threadIdx.x;
  const int jb = blockIdx.x & 7, db = blockIdx.x >> 3;
  const int d0 = db * 64, j0 = jb * 64;

  if (tid < 192) {
    const int r = tid >> 6, d = tid & 63;
    ts[tid] = (r == 0) ? cw[d0 + d] : (r == 1 ? cw[DD + d0 + d] : cbias[d0 + d]);
  }
  __syncthreads();

  const int j = tid & 63, dsub = tid >> 6;
  float a0 = 0.f, a1 = 0.f, a2 = 0.f;
#pragma unroll
  for (int i = 0; i < 16; ++i) {
    const int d = dsub * 16 + i;
    const float w = wv[(d0 + d) * DD + j0 + j];
    a0 = fmaf(ts[d], w, a0);
    a1 = fmaf(ts[64 + d], w, a1);
    a2 = fmaf(ts[128 + d], w, a2);
  }
  red[(dsub * 3 + 0) * 64 + j] = a0;
  red[(dsub * 3 + 1) * 64 + j] = a1;
  red[(dsub * 3 + 2) * 64 + j] = a2;
  __syncthreads();
  if (tid < 192) {
    const int r = tid >> 6, jj = tid & 63;
    pA[(db * 3 + r) * DD + j0 + jj] =
        red[(0 * 3 + r) * 64 + jj] + red[(1 * 3 + r) * 64 + jj] +
        red[(2 * 3 + r) * 64 + jj] + red[(3 * 3 + r) * 64 + jj];
  }
}

// ---------------- K2: pB[db][r][j] = sum_{d in chunk db} A_r[d]*wo[d][j] ----
// A_r[d] = sum_c pA[c][r][d]  (+ bv[d] for r==2)
__global__ __launch_bounds__(256) void k2_b(
    const float* __restrict__ bv, const float* __restrict__ wo,
    const float* __restrict__ pA, float* __restrict__ pB) {
  __shared__ float ts[3 * 64];
  __shared__ float red[4 * 3 * 64];
  const int tid = threadIdx.x;
  const int jb = blockIdx.x & 7, db = blockIdx.x >> 3;
  const int d0 = db * 64, j0 = jb * 64;

  if (tid < 192) {
    const int r = tid >> 6, d = tid & 63;
    float s = 0.f;
#pragma unroll
    for (int c = 0; c < NC; ++c) s += pA[(c * 3 + r) * DD + d0 + d];
    if (r == 2) s += bv[d0 + d];
    ts[tid] = s;
  }
  __syncthreads();

  const int j = tid & 63, dsub = tid >> 6;
  float a0 = 0.f, a1 = 0.f, a2 = 0.f;
#pragma unroll
  for (int i = 0; i < 16; ++i) {
    const int d = dsub * 16 + i;
    const float w = wo[(d0 + d) * DD + j0 + j];
    a0 = fmaf(ts[d], w, a0);
    a1 = fmaf(ts[64 + d], w, a1);
    a2 = fmaf(ts[128 + d], w, a2);
  }
  red[(dsub * 3 + 0) * 64 + j] = a0;
  red[(dsub * 3 + 1) * 64 + j] = a1;
  red[(dsub * 3 + 2) * 64 + j] = a2;
  __syncthreads();
  if (tid < 192) {
    const int r = tid >> 6, jj = tid & 63;
    pB[(db * 3 + r) * DD + j0 + jj] =
        red[(0 * 3 + r) * 64 + jj] + red[(1 * 3 + r) * 64 + jj] +
        red[(2 * 3 + r) * 64 + jj] + red[(3 * 3 + r) * 64 + jj];
  }
}

// ---------------- K3: heads + combine. grid 8 = (half 2 x s 4), 512 threads ----
// B_r[d] = sum_c pB[c][r][d] (+ bo[d] for r==2)
// C_r[o] = sum_d B_r[d] * W[s][d][o];  out[half][b][o] for all b with sid[b]==s
__global__ __launch_bounds__(512) void k3_head(
    const float* __restrict__ cb, const int* __restrict__ sid,
    const float* __restrict__ bo, const float* __restrict__ pB,
    const float* __restrict__ pw, const float* __restrict__ pb,
    const float* __restrict__ aw, const float* __restrict__ ab,
    float* __restrict__ out) {
  __shared__ float Bs[3 * DD];        // 6 KB
  __shared__ float red[8 * 3 * 64];   // 6 KB
  const int tid = threadIdx.x;
  const int s = blockIdx.x & 3, half = blockIdx.x >> 2;

  for (int idx = tid; idx < 3 * DD; idx += 512) {
    const int r = idx >> 9, d = idx & 511;
    float v = 0.f;
#pragma unroll
    for (int c = 0; c < NC; ++c) v += pB[(c * 3 + r) * DD + d];
    if (r == 2) v += bo[d];
    Bs[r * DD + d] = v;
  }
  __syncthreads();

  const int o = tid & 63, dsub = tid >> 6;       // dsub in [0,8), 64 d each
  const float* W = (half ? aw : pw) + s * DD * OO;
  float a0 = 0.f, a1 = 0.f, a2 = 0.f;
#pragma unroll 16
  for (int i = 0; i < 64; ++i) {
    const int d = dsub * 64 + i;
    const float w = W[d * OO + o];
    a0 = fmaf(Bs[d], w, a0);
    a1 = fmaf(Bs[DD + d], w, a1);
    a2 = fmaf(Bs[2 * DD + d], w, a2);
  }
  red[(dsub * 3 + 0) * 64 + o] = a0;
  red[(dsub * 3 + 1) * 64 + o] = a1;
  red[(dsub * 3 + 2) * 64 + o] = a2;
  __syncthreads();
  if (tid < OO) {
    float c0 = 0.f, c1 = 0.f, c2 = 0.f;
#pragma unroll
    for (int p = 0; p < 8; ++p) {
      c0 += red[(p * 3 + 0) * 64 + tid];
      c1 += red[(p * 3 + 1) * 64 + tid];
      c2 += red[(p * 3 + 2) * 64 + tid];
    }
    const float bias = (half ? ab : pb)[s * OO + tid];
    for (int b = 0; b < BB; ++b) {
      if (sid[b] == s) {
        out[half * (BB * OO) + b * OO + tid] =
            fmaf(cb[2 * b], c0, fmaf(cb[2 * b + 1], c1, c2 + bias));
      }
    }
  }
}

extern "C" void kernel_launch(void* const* d_in, const int* in_sizes, int n_in,
                              void* d_out, int out_size, void* d_ws, size_t ws_size,
                              hipStream_t stream) {
  // setup_inputs() order:
  // 0 x_batch 1 context_batch 2 specialist_ids 3 emb_table 4 wqkv 5 bqkv 6 wo 7 bo
  // 8 ln1_g 9 ln1_b 10 w1 11 b1 12 w2 13 b2 14 ln2_g 15 ln2_b 16 ctx_w 17 ctx_b
  // 18 ca_wq 19 ca_bq 20 ca_wk 21 ca_bk 22 ca_wv 23 ca_bv 24 ca_wo 25 ca_bo
  // 26 pred_w 27 pred_b 28 act_w 29 act_b
  const float* cb    = reinterpret_cast<const float*>(d_in[1]);
  const int*   sid   = reinterpret_cast<const int*>(d_in[2]);
  const float* cw    = reinterpret_cast<const float*>(d_in[16]);
  const float* cbias = reinterpret_cast<const float*>(d_in[17]);
  const float* wv    = reinterpret_cast<const float*>(d_in[22]);
  const float* bv    = reinterpret_cast<const float*>(d_in[23]);
  const float* wo    = reinterpret_cast<const float*>(d_in[24]);
  const float* bo    = reinterpret_cast<const float*>(d_in[25]);
  const float* pw    = reinterpret_cast<const float*>(d_in[26]);
  const float* pb    = reinterpret_cast<const float*>(d_in[27]);
  const float* aw    = reinterpret_cast<const float*>(d_in[28]);
  const float* ab    = reinterpret_cast<const float*>(d_in[29]);

  float* pA = reinterpret_cast<float*>(d_ws);    // [8][3][512]
  float* pB = pA + NC * 3 * DD;                  // [8][3][512]
  float* out = reinterpret_cast<float*>(d_out);

  k1_a   <<<64, 256, 0, stream>>>(cw, cbias, wv, pA);
  k2_b   <<<64, 256, 0, stream>>>(bv, wo, pA, pB);
  k3_head<<<8, 512, 0, stream>>>(cb, sid, bo, pB, pw, pb, aw, ab, out);
}